// Round 4
// baseline (369.958 us; speedup 1.0000x reference)
//
#include <hip/hip_runtime.h>

#define B_  32
#define LC_ 2048
#define LQ_ 256
#define D_  256
#define NEGH (-30000.0f)   // f16-safe mask value

typedef _Float16 f16;
typedef _Float16 f16x4 __attribute__((ext_vector_type(4)));
typedef _Float16 f16x8 __attribute__((ext_vector_type(8)));
typedef float    f32x4 __attribute__((ext_vector_type(4)));

// ---- K1: cast ctx->f16, qry->qry*wm f16; sc = ctx.wc, sq = qry.wq ----
__global__ __launch_bounds__(256) void k_prep(
    const float* __restrict__ ctx, const float* __restrict__ qry,
    const float* __restrict__ w0, f16* __restrict__ ctx16,
    f16* __restrict__ qrywm16, float* __restrict__ sc, float* __restrict__ sq)
{
    const int lane = threadIdx.x & 63;
    const int wave = threadIdx.x >> 6;
    const int row  = blockIdx.x * 4 + wave;
    const int NC = B_ * LC_;
    if (row < NC) {
        float4 v = *(const float4*)(ctx + (long long)row * D_ + lane * 4);
        f16x4 h; h[0] = (f16)v.x; h[1] = (f16)v.y; h[2] = (f16)v.z; h[3] = (f16)v.w;
        *(f16x4*)(ctx16 + (long long)row * D_ + lane * 4) = h;
        float4 wc = *(const float4*)(w0 + lane * 4);
        float s = v.x*wc.x + v.y*wc.y + v.z*wc.z + v.w*wc.w;
        #pragma unroll
        for (int off = 32; off > 0; off >>= 1) s += __shfl_down(s, off, 64);
        if (lane == 0) sc[row] = s;
    } else {
        int r = row - NC;
        float4 v = *(const float4*)(qry + (long long)r * D_ + lane * 4);
        float4 wm = *(const float4*)(w0 + 2 * D_ + lane * 4);
        f16x4 h;
        h[0] = (f16)(v.x * wm.x); h[1] = (f16)(v.y * wm.y);
        h[2] = (f16)(v.z * wm.z); h[3] = (f16)(v.w * wm.w);
        *(f16x4*)(qrywm16 + (long long)r * D_ + lane * 4) = h;
        float4 wq = *(const float4*)(w0 + D_ + lane * 4);
        float s = v.x*wq.x + v.y*wq.y + v.z*wq.z + v.w*wq.w;
        #pragma unroll
        for (int off = 32; off > 0; off >>= 1) s += __shfl_down(s, off, 64);
        if (lane == 0) sq[r] = s;
    }
}

// ---- K2: transpose qry fp32 [q][d] -> f16 Bcat[0:256] rows [d][q] ----
__global__ __launch_bounds__(256) void k_tq(
    const float* __restrict__ in, f16* __restrict__ out)
{
    __shared__ float tile[64 * 65];
    const int b = blockIdx.z;
    const int r0 = blockIdx.x * 64, c0 = blockIdx.y * 64;
    const int t = threadIdx.x;
    const float* ib = in + (long long)b * LQ_ * D_;
    #pragma unroll
    for (int p = 0; p < 4; ++p) {
        int r = (t >> 4) + p * 16;
        int cb = (t & 15) * 4;
        float4 v = *(const float4*)(ib + (long long)(r0 + r) * D_ + c0 + cb);
        tile[r * 65 + cb + 0] = v.x;
        tile[r * 65 + cb + 1] = v.y;
        tile[r * 65 + cb + 2] = v.z;
        tile[r * 65 + cb + 3] = v.w;
    }
    __syncthreads();
    f16* ob = out + (long long)b * 512 * LQ_;
    #pragma unroll
    for (int p = 0; p < 4; ++p) {
        int c = (t >> 4) + p * 16;
        int rb = (t & 15) * 4;
        f16x4 h;
        h[0] = (f16)tile[(rb + 0) * 65 + c];
        h[1] = (f16)tile[(rb + 1) * 65 + c];
        h[2] = (f16)tile[(rb + 2) * 65 + c];
        h[3] = (f16)tile[(rb + 3) * 65 + c];
        *(f16x4*)(ob + (long long)(c0 + c) * LQ_ + r0 + rb) = h;
    }
}

// ---- F1: sim GEMM (direct A-frags) + mask + sim16 + row stats + column partials ----
__global__ __launch_bounds__(256) void k_f1(
    const f16* __restrict__ ctx16, const f16* __restrict__ qrywm16,
    const float* __restrict__ sc, const float* __restrict__ sq,
    const int* __restrict__ cmask, const int* __restrict__ qmask,
    f16* __restrict__ sim16, float* __restrict__ rowm_g, float* __restrict__ rowinvl_g,
    float* __restrict__ pm, float* __restrict__ pl)
{
    __shared__ f16 Bs[256 * 40];
    const int b = blockIdx.y, c0 = blockIdx.x * 128;
    const int t = threadIdx.x, lane = t & 63, wv = t >> 6;
    const int l15 = lane & 15, quad = lane >> 4;
    const int wm = wv * 32;
    const f16* Ab = ctx16 + ((long long)b * LC_ + c0 + wm) * D_;
    const f16* Bb = qrywm16 + (long long)b * LQ_ * D_;
    f32x4 acc[2][16] = {};
    for (int k0 = 0; k0 < D_; k0 += 32) {
        #pragma unroll
        for (int g = 0; g < 4; ++g)
            *(f16x8*)(Bs + t * 40 + g * 8) = *(const f16x8*)(Bb + (long long)t * D_ + k0 + g * 8);
        f16x8 af[2];
        #pragma unroll
        for (int i = 0; i < 2; ++i)
            af[i] = *(const f16x8*)(Ab + (long long)(i * 16 + l15) * D_ + k0 + quad * 8);
        __syncthreads();
        #pragma unroll
        for (int j = 0; j < 16; ++j) {
            f16x8 bf = *(const f16x8*)(Bs + (j * 16 + l15) * 40 + quad * 8);
            acc[0][j] = __builtin_amdgcn_mfma_f32_16x16x32_f16(af[0], bf, acc[0][j], 0, 0, 0);
            acc[1][j] = __builtin_amdgcn_mfma_f32_16x16x32_f16(af[1], bf, acc[1][j], 0, 0, 0);
        }
        __syncthreads();
    }
    // per-lane coordinates: c = c0+wm+i*16+quad*4+r ; q = j*16+l15
    float scv[8]; int cmv[8];
    #pragma unroll
    for (int i = 0; i < 2; ++i)
        #pragma unroll
        for (int r = 0; r < 4; ++r) {
            int c = c0 + wm + i * 16 + quad * 4 + r;
            scv[i * 4 + r] = sc[b * LC_ + c];
            cmv[i * 4 + r] = cmask[b * LC_ + c];
        }
    float sqv[16]; int qmv[16];
    #pragma unroll
    for (int j = 0; j < 16; ++j) {
        int q = j * 16 + l15;
        sqv[j] = sq[b * LQ_ + q];
        qmv[j] = qmask[b * LQ_ + q];
    }
    #pragma unroll
    for (int i = 0; i < 2; ++i)
        #pragma unroll
        for (int j = 0; j < 16; ++j)
            #pragma unroll
            for (int r = 0; r < 4; ++r) {
                float v = acc[i][j][r] + scv[i * 4 + r] + sqv[j];
                acc[i][j][r] = (cmv[i * 4 + r] | qmv[j]) ? NEGH : v;
            }
    // write sim16
    #pragma unroll
    for (int i = 0; i < 2; ++i)
        #pragma unroll
        for (int r = 0; r < 4; ++r) {
            f16* orow = sim16 + ((long long)b * LC_ + c0 + wm + i * 16 + quad * 4 + r) * LQ_ + l15;
            #pragma unroll
            for (int j = 0; j < 16; ++j) orow[j * 16] = (f16)acc[i][j][r];
        }
    // column partials over this wave's 32 c
    #pragma unroll
    for (int j = 0; j < 16; ++j) {
        float m = -INFINITY;
        #pragma unroll
        for (int i = 0; i < 2; ++i)
            #pragma unroll
            for (int r = 0; r < 4; ++r) m = fmaxf(m, acc[i][j][r]);
        m = fmaxf(m, __shfl_xor(m, 16, 64));
        m = fmaxf(m, __shfl_xor(m, 32, 64));
        float l = 0.f;
        #pragma unroll
        for (int i = 0; i < 2; ++i)
            #pragma unroll
            for (int r = 0; r < 4; ++r) l += __expf(acc[i][j][r] - m);
        l += __shfl_xor(l, 16, 64);
        l += __shfl_xor(l, 32, 64);
        if (quad == 0) {
            int idx = (b * 64 + blockIdx.x * 4 + wv) * LQ_ + j * 16 + l15;
            pm[idx] = m; pl[idx] = l;
        }
    }
    // row stats over q=256
    #pragma unroll
    for (int i = 0; i < 2; ++i)
        #pragma unroll
        for (int r = 0; r < 4; ++r) {
            float m = -INFINITY;
            #pragma unroll
            for (int j = 0; j < 16; ++j) m = fmaxf(m, acc[i][j][r]);
            m = fmaxf(m, __shfl_xor(m, 1, 64));
            m = fmaxf(m, __shfl_xor(m, 2, 64));
            m = fmaxf(m, __shfl_xor(m, 4, 64));
            m = fmaxf(m, __shfl_xor(m, 8, 64));
            float l = 0.f;
            #pragma unroll
            for (int j = 0; j < 16; ++j) l += __expf(acc[i][j][r] - m);
            l += __shfl_xor(l, 1, 64);
            l += __shfl_xor(l, 2, 64);
            l += __shfl_xor(l, 4, 64);
            l += __shfl_xor(l, 8, 64);
            if (l15 == 0) {
                int c = c0 + wm + i * 16 + quad * 4 + r;
                rowm_g[b * LC_ + c] = m;
                rowinvl_g[b * LC_ + c] = 1.0f / l;
            }
        }
}

__global__ __launch_bounds__(256) void k_colreduce(
    const float* __restrict__ pm, const float* __restrict__ pl,
    float* __restrict__ colm, float* __restrict__ colinvl)
{
    const int col = blockIdx.x * 256 + threadIdx.x;
    const int b = col >> 8, q = col & 255;
    float M = -INFINITY, L = 0.f;
    for (int ch = 0; ch < 64; ++ch) {
        int idx = (b * 64 + ch) * LQ_ + q;
        float m = pm[idx], l = pl[idx];
        float nM = fmaxf(M, m);
        L = L * __expf(M - nM) + l * __expf(m - nM);
        M = nM;
    }
    colm[col] = M; colinvl[col] = 1.0f / L;
}

// ---- G3: Tt[d][q] = colinvl[q] * sum_c ctx[c][d]*exp(sim[c][q]-colm[q]) -> Bcat[256+d][q] ----
#define LDA3 66
__global__ __launch_bounds__(256) void k_g3(
    const f16* __restrict__ ctx16, const f16* __restrict__ sim16,
    const float* __restrict__ colm, const float* __restrict__ colinvl,
    f16* __restrict__ Bcat)
{
    __shared__ f16 As[128 * LDA3];   // [d][c]
    __shared__ f16 Bs[64 * LDA3];    // [q][c]
    __shared__ float colm_s[64], cil_s[64];
    const int b = blockIdx.x;
    const int combo = blockIdx.y;
    const int qt = combo & 3, dh = combo >> 2;
    const int q0 = qt * 64, d0 = dh * 128;
    const int t = threadIdx.x, lane = t & 63, wv = t >> 6;
    const int wm_off = (wv >> 1) * 64, wn_off = (wv & 1) * 32;
    if (t < 64) {
        colm_s[t] = colm[b * LQ_ + q0 + t];
        cil_s[t]  = colinvl[b * LQ_ + q0 + t];
    }
    __syncthreads();
    const f16* Ab = ctx16 + (long long)b * LC_ * D_;
    const f16* Sb = sim16 + (long long)b * LC_ * LQ_;
    f32x4 acc[4][2] = {};
    const int acc_ = t >> 4, ad8 = (t & 15) * 8;
    const int bcc = t >> 3, bq8 = (t & 7) * 8;
    for (int c0 = 0; c0 < LC_; c0 += 64) {
        #pragma unroll
        for (int p = 0; p < 4; ++p) {
            int cc = acc_ + p * 16;
            f16x8 h = *(const f16x8*)(Ab + (long long)(c0 + cc) * D_ + d0 + ad8);
            #pragma unroll
            for (int j = 0; j < 8; ++j)
                As[(ad8 + j) * LDA3 + cc] = h[j];
        }
        #pragma unroll
        for (int p = 0; p < 2; ++p) {
            int cc = bcc + p * 32;
            f16x8 h = *(const f16x8*)(Sb + (long long)(c0 + cc) * LQ_ + q0 + bq8);
            #pragma unroll
            for (int j = 0; j < 8; ++j)
                Bs[(bq8 + j) * LDA3 + cc] = (f16)__expf((float)h[j] - colm_s[bq8 + j]);
        }
        __syncthreads();
        #pragma unroll
        for (int kk = 0; kk < 64; kk += 32) {
            f16x8 af[4], bf[2];
            #pragma unroll
            for (int i = 0; i < 4; ++i)
                af[i] = *(const f16x8*)(As + (wm_off + i * 16 + (lane & 15)) * LDA3 + kk + (lane >> 4) * 8);
            #pragma unroll
            for (int j = 0; j < 2; ++j)
                bf[j] = *(const f16x8*)(Bs + (wn_off + j * 16 + (lane & 15)) * LDA3 + kk + (lane >> 4) * 8);
            #pragma unroll
            for (int i = 0; i < 4; ++i)
                #pragma unroll
                for (int j = 0; j < 2; ++j)
                    acc[i][j] = __builtin_amdgcn_mfma_f32_16x16x32_f16(af[i], bf[j], acc[i][j], 0, 0, 0);
        }
        __syncthreads();
    }
    #pragma unroll
    for (int i = 0; i < 4; ++i) {
        #pragma unroll
        for (int r = 0; r < 4; ++r) {
            int d = d0 + wm_off + i * 16 + (lane >> 4) * 4 + r;
            f16* orow = Bcat + (long long)b * 512 * LQ_ + (long long)(256 + d) * LQ_ + q0 + wn_off + (lane & 15);
            #pragma unroll
            for (int j = 0; j < 2; ++j)
                orow[j * 16] = (f16)(acc[i][j][r] * cil_s[wn_off + j * 16 + (lane & 15)]);
        }
    }
}

// ---- F45: [A | Bmat] LDS-free. Wave pair splits N=512 (qryT rows / Tt rows). ----
__global__ __launch_bounds__(256) void k_f45(
    const f16* __restrict__ sim16, const float* __restrict__ rowm,
    const float* __restrict__ rowinvl, const f16* __restrict__ Bcat,
    float* __restrict__ outA, float* __restrict__ outB)
{
    const int b = blockIdx.y, c0 = blockIdx.x * 64;
    const int t = threadIdx.x, lane = t & 63, wv = t >> 6;
    const int l15 = lane & 15, quad = lane >> 4;
    const int ch = (wv >> 1) * 32;   // c-half
    const int nh = wv & 1;           // 0: A, 1: Bmat
    const f16* Ab = sim16 + ((long long)b * LC_ + c0 + ch) * LQ_;
    const f16* Bb = Bcat + ((long long)b * 512 + nh * 256) * LQ_;
    float rm2[2];
    #pragma unroll
    for (int i = 0; i < 2; ++i)
        rm2[i] = rowm[b * LC_ + c0 + ch + i * 16 + l15];
    f32x4 acc[2][16] = {};
    for (int k0 = 0; k0 < LQ_; k0 += 32) {
        f16x8 af[2];
        #pragma unroll
        for (int i = 0; i < 2; ++i) {
            f16x8 s8 = *(const f16x8*)(Ab + (long long)(i * 16 + l15) * LQ_ + k0 + quad * 8);
            #pragma unroll
            for (int jj = 0; jj < 8; ++jj)
                af[i][jj] = (f16)__expf((float)s8[jj] - rm2[i]);
        }
        #pragma unroll
        for (int j = 0; j < 16; ++j) {
            f16x8 bf = *(const f16x8*)(Bb + (long long)(j * 16 + l15) * LQ_ + k0 + quad * 8);
            acc[0][j] = __builtin_amdgcn_mfma_f32_16x16x32_f16(af[0], bf, acc[0][j], 0, 0, 0);
            acc[1][j] = __builtin_amdgcn_mfma_f32_16x16x32_f16(af[1], bf, acc[1][j], 0, 0, 0);
        }
    }
    float* outp = nh ? outB : outA;
    #pragma unroll
    for (int i = 0; i < 2; ++i)
        #pragma unroll
        for (int r = 0; r < 4; ++r) {
            int c = c0 + ch + i * 16 + quad * 4 + r;
            float ri = rowinvl[b * LC_ + c];
            float* orow = outp + ((long long)b * LC_ + c) * D_ + l15;
            #pragma unroll
            for (int j = 0; j < 16; ++j)
                orow[j * 16] = acc[i][j][r] * ri;
        }
}

extern "C" void kernel_launch(void* const* d_in, const int* in_sizes, int n_in,
                              void* d_out, int out_size, void* d_ws, size_t ws_size,
                              hipStream_t stream) {
    const float* ctx   = (const float*)d_in[0];
    const float* qry   = (const float*)d_in[1];
    const int*   cmask = (const int*)d_in[2];
    const int*   qmask = (const int*)d_in[3];
    const float* w0    = (const float*)d_in[4];
    float* out = (float*)d_out;

    char* w = (char*)d_ws;
    float* sc      = (float*)w;  w += (long long)65536 * 4;
    float* sq      = (float*)w;  w += (long long)8192 * 4;
    float* rowm    = (float*)w;  w += (long long)65536 * 4;
    float* rowinvl = (float*)w;  w += (long long)65536 * 4;
    float* colm    = (float*)w;  w += (long long)8192 * 4;
    float* colinvl = (float*)w;  w += (long long)8192 * 4;
    float* pm      = (float*)w;  w += (long long)524288 * 4;
    float* pl      = (float*)w;  w += (long long)524288 * 4;
    f16*   sim16   = (f16*)w;    w += (long long)16777216 * 2;
    f16*   ctx16   = (f16*)w;    w += (long long)16777216 * 2;
    f16*   qrywm16 = (f16*)w;    w += (long long)2097152 * 2;
    f16*   Bcat    = (f16*)w;    w += (long long)4194304 * 2;

    k_prep<<<18432, 256, 0, stream>>>(ctx, qry, w0, ctx16, qrywm16, sc, sq);
    k_tq<<<dim3(4, 4, 32), 256, 0, stream>>>(qry, Bcat);
    k_f1<<<dim3(16, 32), 256, 0, stream>>>(ctx16, qrywm16, sc, sq, cmask, qmask,
        sim16, rowm, rowinvl, pm, pl);
    k_colreduce<<<32, 256, 0, stream>>>(pm, pl, colm, colinvl);
    k_g3<<<dim3(32, 8), 256, 0, stream>>>(ctx16, sim16, colm, colinvl, Bcat);
    k_f45<<<dim3(32, 32), 256, 0, stream>>>(sim16, rowm, rowinvl, Bcat,
        out, out + (long long)B_ * LC_ * D_);
}

// Round 5
// 352.011 us; speedup vs baseline: 1.0510x; 1.0510x over previous
//
#include <hip/hip_runtime.h>

#define B_  32
#define LC_ 2048
#define LQ_ 256
#define D_  256
#define NEGH (-30000.0f)   // f16-safe mask value

typedef _Float16 f16;
typedef _Float16 f16x4 __attribute__((ext_vector_type(4)));
typedef _Float16 f16x8 __attribute__((ext_vector_type(8)));
typedef float    f32x4 __attribute__((ext_vector_type(4)));

// ---- K1: cast ctx->f16, qry->qry*wm f16; sc = ctx.wc, sq = qry.wq ----
__global__ __launch_bounds__(256) void k_prep(
    const float* __restrict__ ctx, const float* __restrict__ qry,
    const float* __restrict__ w0, f16* __restrict__ ctx16,
    f16* __restrict__ qrywm16, float* __restrict__ sc, float* __restrict__ sq)
{
    const int lane = threadIdx.x & 63;
    const int wave = threadIdx.x >> 6;
    const int row  = blockIdx.x * 4 + wave;
    const int NC = B_ * LC_;
    if (row < NC) {
        float4 v = *(const float4*)(ctx + (long long)row * D_ + lane * 4);
        f16x4 h; h[0] = (f16)v.x; h[1] = (f16)v.y; h[2] = (f16)v.z; h[3] = (f16)v.w;
        *(f16x4*)(ctx16 + (long long)row * D_ + lane * 4) = h;
        float4 wc = *(const float4*)(w0 + lane * 4);
        float s = v.x*wc.x + v.y*wc.y + v.z*wc.z + v.w*wc.w;
        #pragma unroll
        for (int off = 32; off > 0; off >>= 1) s += __shfl_down(s, off, 64);
        if (lane == 0) sc[row] = s;
    } else {
        int r = row - NC;
        float4 v = *(const float4*)(qry + (long long)r * D_ + lane * 4);
        float4 wm = *(const float4*)(w0 + 2 * D_ + lane * 4);
        f16x4 h;
        h[0] = (f16)(v.x * wm.x); h[1] = (f16)(v.y * wm.y);
        h[2] = (f16)(v.z * wm.z); h[3] = (f16)(v.w * wm.w);
        *(f16x4*)(qrywm16 + (long long)r * D_ + lane * 4) = h;
        float4 wq = *(const float4*)(w0 + D_ + lane * 4);
        float s = v.x*wq.x + v.y*wq.y + v.z*wq.z + v.w*wq.w;
        #pragma unroll
        for (int off = 32; off > 0; off >>= 1) s += __shfl_down(s, off, 64);
        if (lane == 0) sq[r] = s;
    }
}

// ---- K2: transpose qry fp32 [q][d] -> f16 Bcat[0:256] rows [d][q] ----
__global__ __launch_bounds__(256) void k_tq(
    const float* __restrict__ in, f16* __restrict__ out)
{
    __shared__ float tile[64 * 65];
    const int b = blockIdx.z;
    const int r0 = blockIdx.x * 64, c0 = blockIdx.y * 64;
    const int t = threadIdx.x;
    const float* ib = in + (long long)b * LQ_ * D_;
    #pragma unroll
    for (int p = 0; p < 4; ++p) {
        int r = (t >> 4) + p * 16;
        int cb = (t & 15) * 4;
        float4 v = *(const float4*)(ib + (long long)(r0 + r) * D_ + c0 + cb);
        tile[r * 65 + cb + 0] = v.x;
        tile[r * 65 + cb + 1] = v.y;
        tile[r * 65 + cb + 2] = v.z;
        tile[r * 65 + cb + 3] = v.w;
    }
    __syncthreads();
    f16* ob = out + (long long)b * 512 * LQ_;
    #pragma unroll
    for (int p = 0; p < 4; ++p) {
        int c = (t >> 4) + p * 16;
        int rb = (t & 15) * 4;
        f16x4 h;
        h[0] = (f16)tile[(rb + 0) * 65 + c];
        h[1] = (f16)tile[(rb + 1) * 65 + c];
        h[2] = (f16)tile[(rb + 2) * 65 + c];
        h[3] = (f16)tile[(rb + 3) * 65 + c];
        *(f16x4*)(ob + (long long)(c0 + c) * LQ_ + r0 + rb) = h;
    }
}

// ---- F1: sim GEMM (direct A-frags, LDS B) + mask + sim16 + row stats + column partials ----
__global__ __launch_bounds__(256) void k_f1(
    const f16* __restrict__ ctx16, const f16* __restrict__ qrywm16,
    const float* __restrict__ sc, const float* __restrict__ sq,
    const int* __restrict__ cmask, const int* __restrict__ qmask,
    f16* __restrict__ sim16, float* __restrict__ rowm_g, float* __restrict__ rowinvl_g,
    float* __restrict__ pm, float* __restrict__ pl)
{
    __shared__ f16 Bs[256 * 40];
    const int b = blockIdx.y, c0 = blockIdx.x * 128;
    const int t = threadIdx.x, lane = t & 63, wv = t >> 6;
    const int l15 = lane & 15, quad = lane >> 4;
    const int wm = wv * 32;
    const f16* Ab = ctx16 + ((long long)b * LC_ + c0 + wm) * D_;
    const f16* Bb = qrywm16 + (long long)b * LQ_ * D_;
    f32x4 acc[2][16] = {};
    for (int k0 = 0; k0 < D_; k0 += 32) {
        #pragma unroll
        for (int g = 0; g < 4; ++g)
            *(f16x8*)(Bs + t * 40 + g * 8) = *(const f16x8*)(Bb + (long long)t * D_ + k0 + g * 8);
        f16x8 af[2];
        #pragma unroll
        for (int i = 0; i < 2; ++i)
            af[i] = *(const f16x8*)(Ab + (long long)(i * 16 + l15) * D_ + k0 + quad * 8);
        __syncthreads();
        #pragma unroll
        for (int j = 0; j < 16; ++j) {
            f16x8 bf = *(const f16x8*)(Bs + (j * 16 + l15) * 40 + quad * 8);
            acc[0][j] = __builtin_amdgcn_mfma_f32_16x16x32_f16(af[0], bf, acc[0][j], 0, 0, 0);
            acc[1][j] = __builtin_amdgcn_mfma_f32_16x16x32_f16(af[1], bf, acc[1][j], 0, 0, 0);
        }
        __syncthreads();
    }
    // per-lane coordinates: c = c0+wm+i*16+quad*4+r ; q = j*16+l15
    float scv[8]; int cmv[8];
    #pragma unroll
    for (int i = 0; i < 2; ++i)
        #pragma unroll
        for (int r = 0; r < 4; ++r) {
            int c = c0 + wm + i * 16 + quad * 4 + r;
            scv[i * 4 + r] = sc[b * LC_ + c];
            cmv[i * 4 + r] = cmask[b * LC_ + c];
        }
    float sqv[16]; int qmv[16];
    #pragma unroll
    for (int j = 0; j < 16; ++j) {
        int q = j * 16 + l15;
        sqv[j] = sq[b * LQ_ + q];
        qmv[j] = qmask[b * LQ_ + q];
    }
    #pragma unroll
    for (int i = 0; i < 2; ++i)
        #pragma unroll
        for (int j = 0; j < 16; ++j)
            #pragma unroll
            for (int r = 0; r < 4; ++r) {
                float v = acc[i][j][r] + scv[i * 4 + r] + sqv[j];
                acc[i][j][r] = (cmv[i * 4 + r] | qmv[j]) ? NEGH : v;
            }
    // write sim16
    #pragma unroll
    for (int i = 0; i < 2; ++i)
        #pragma unroll
        for (int r = 0; r < 4; ++r) {
            f16* orow = sim16 + ((long long)b * LC_ + c0 + wm + i * 16 + quad * 4 + r) * LQ_ + l15;
            #pragma unroll
            for (int j = 0; j < 16; ++j) orow[j * 16] = (f16)acc[i][j][r];
        }
    // column partials over this wave's 32 c
    #pragma unroll
    for (int j = 0; j < 16; ++j) {
        float m = -INFINITY;
        #pragma unroll
        for (int i = 0; i < 2; ++i)
            #pragma unroll
            for (int r = 0; r < 4; ++r) m = fmaxf(m, acc[i][j][r]);
        m = fmaxf(m, __shfl_xor(m, 16, 64));
        m = fmaxf(m, __shfl_xor(m, 32, 64));
        float l = 0.f;
        #pragma unroll
        for (int i = 0; i < 2; ++i)
            #pragma unroll
            for (int r = 0; r < 4; ++r) l += __expf(acc[i][j][r] - m);
        l += __shfl_xor(l, 16, 64);
        l += __shfl_xor(l, 32, 64);
        if (quad == 0) {
            int idx = (b * 64 + blockIdx.x * 4 + wv) * LQ_ + j * 16 + l15;
            pm[idx] = m; pl[idx] = l;
        }
    }
    // row stats over q=256
    #pragma unroll
    for (int i = 0; i < 2; ++i)
        #pragma unroll
        for (int r = 0; r < 4; ++r) {
            float m = -INFINITY;
            #pragma unroll
            for (int j = 0; j < 16; ++j) m = fmaxf(m, acc[i][j][r]);
            m = fmaxf(m, __shfl_xor(m, 1, 64));
            m = fmaxf(m, __shfl_xor(m, 2, 64));
            m = fmaxf(m, __shfl_xor(m, 4, 64));
            m = fmaxf(m, __shfl_xor(m, 8, 64));
            float l = 0.f;
            #pragma unroll
            for (int j = 0; j < 16; ++j) l += __expf(acc[i][j][r] - m);
            l += __shfl_xor(l, 1, 64);
            l += __shfl_xor(l, 2, 64);
            l += __shfl_xor(l, 4, 64);
            l += __shfl_xor(l, 8, 64);
            if (l15 == 0) {
                int c = c0 + wm + i * 16 + quad * 4 + r;
                rowm_g[b * LC_ + c] = m;
                rowinvl_g[b * LC_ + c] = 1.0f / l;
            }
        }
}

__global__ __launch_bounds__(256) void k_colreduce(
    const float* __restrict__ pm, const float* __restrict__ pl,
    float* __restrict__ colm, float* __restrict__ colinvl)
{
    const int col = blockIdx.x * 256 + threadIdx.x;
    const int b = col >> 8, q = col & 255;
    float M = -INFINITY, L = 0.f;
    for (int ch = 0; ch < 64; ++ch) {
        int idx = (b * 64 + ch) * LQ_ + q;
        float m = pm[idx], l = pl[idx];
        float nM = fmaxf(M, m);
        L = L * __expf(M - nM) + l * __expf(m - nM);
        M = nM;
    }
    colm[col] = M; colinvl[col] = 1.0f / L;
}

// ---- G3: Tt[d][q] = colinvl[q] * sum_c ctx[c][d]*exp(sim[c][q]-colm[q]) -> Bcat[256+d][q] ----
#define LDA3 66
__global__ __launch_bounds__(256) void k_g3(
    const f16* __restrict__ ctx16, const f16* __restrict__ sim16,
    const float* __restrict__ colm, const float* __restrict__ colinvl,
    f16* __restrict__ Bcat)
{
    __shared__ f16 As[128 * LDA3];   // [d][c]
    __shared__ f16 Bs[64 * LDA3];    // [q][c]
    __shared__ float colm_s[64], cil_s[64];
    const int b = blockIdx.x;
    const int combo = blockIdx.y;
    const int qt = combo & 3, dh = combo >> 2;
    const int q0 = qt * 64, d0 = dh * 128;
    const int t = threadIdx.x, lane = t & 63, wv = t >> 6;
    const int wm_off = (wv >> 1) * 64, wn_off = (wv & 1) * 32;
    if (t < 64) {
        colm_s[t] = colm[b * LQ_ + q0 + t];
        cil_s[t]  = colinvl[b * LQ_ + q0 + t];
    }
    __syncthreads();
    const f16* Ab = ctx16 + (long long)b * LC_ * D_;
    const f16* Sb = sim16 + (long long)b * LC_ * LQ_;
    f32x4 acc[4][2] = {};
    const int acc_ = t >> 4, ad8 = (t & 15) * 8;
    const int bcc = t >> 3, bq8 = (t & 7) * 8;
    for (int c0 = 0; c0 < LC_; c0 += 64) {
        #pragma unroll
        for (int p = 0; p < 4; ++p) {
            int cc = acc_ + p * 16;
            f16x8 h = *(const f16x8*)(Ab + (long long)(c0 + cc) * D_ + d0 + ad8);
            #pragma unroll
            for (int j = 0; j < 8; ++j)
                As[(ad8 + j) * LDA3 + cc] = h[j];
        }
        #pragma unroll
        for (int p = 0; p < 2; ++p) {
            int cc = bcc + p * 32;
            f16x8 h = *(const f16x8*)(Sb + (long long)(c0 + cc) * LQ_ + q0 + bq8);
            #pragma unroll
            for (int j = 0; j < 8; ++j)
                Bs[(bq8 + j) * LDA3 + cc] = (f16)__expf((float)h[j] - colm_s[bq8 + j]);
        }
        __syncthreads();
        #pragma unroll
        for (int kk = 0; kk < 64; kk += 32) {
            f16x8 af[4], bf[2];
            #pragma unroll
            for (int i = 0; i < 4; ++i)
                af[i] = *(const f16x8*)(As + (wm_off + i * 16 + (lane & 15)) * LDA3 + kk + (lane >> 4) * 8);
            #pragma unroll
            for (int j = 0; j < 2; ++j)
                bf[j] = *(const f16x8*)(Bs + (wn_off + j * 16 + (lane & 15)) * LDA3 + kk + (lane >> 4) * 8);
            #pragma unroll
            for (int i = 0; i < 4; ++i)
                #pragma unroll
                for (int j = 0; j < 2; ++j)
                    acc[i][j] = __builtin_amdgcn_mfma_f32_16x16x32_f16(af[i], bf[j], acc[i][j], 0, 0, 0);
        }
        __syncthreads();
    }
    #pragma unroll
    for (int i = 0; i < 4; ++i) {
        #pragma unroll
        for (int r = 0; r < 4; ++r) {
            int d = d0 + wm_off + i * 16 + (lane >> 4) * 4 + r;
            f16* orow = Bcat + (long long)b * 512 * LQ_ + (long long)(256 + d) * LQ_ + q0 + wn_off + (lane & 15);
            #pragma unroll
            for (int j = 0; j < 2; ++j)
                orow[j * 16] = (f16)(acc[i][j][r] * cil_s[wn_off + j * 16 + (lane & 15)]);
        }
    }
}

// ---- F45 v2: [A | Bmat], f1 structure: direct A-frags from sim16 (+exp), LDS-staged B ----
__global__ __launch_bounds__(256) void k_f45(
    const f16* __restrict__ sim16, const float* __restrict__ rowm,
    const float* __restrict__ rowinvl, const f16* __restrict__ Bcat,
    float* __restrict__ outA, float* __restrict__ outB)
{
    __shared__ f16 Bs[256 * 40];
    const int b = blockIdx.z, c0 = blockIdx.x * 128, nh = blockIdx.y;
    const int t = threadIdx.x, lane = t & 63, wv = t >> 6;
    const int l15 = lane & 15, quad = lane >> 4;
    const int wm = wv * 32;
    const f16* Ab = sim16 + ((long long)b * LC_ + c0 + wm) * LQ_;
    const f16* Bb = Bcat + ((long long)b * 512 + nh * 256) * LQ_;
    float rm2[2];
    #pragma unroll
    for (int i = 0; i < 2; ++i)
        rm2[i] = rowm[b * LC_ + c0 + wm + i * 16 + l15];
    f32x4 acc[2][16] = {};
    for (int k0 = 0; k0 < LQ_; k0 += 32) {
        #pragma unroll
        for (int g = 0; g < 4; ++g)
            *(f16x8*)(Bs + t * 40 + g * 8) = *(const f16x8*)(Bb + (long long)t * LQ_ + k0 + g * 8);
        f16x8 af[2];
        #pragma unroll
        for (int i = 0; i < 2; ++i) {
            f16x8 s8 = *(const f16x8*)(Ab + (long long)(i * 16 + l15) * LQ_ + k0 + quad * 8);
            #pragma unroll
            for (int jj = 0; jj < 8; ++jj)
                af[i][jj] = (f16)__expf((float)s8[jj] - rm2[i]);
        }
        __syncthreads();
        #pragma unroll
        for (int j = 0; j < 16; ++j) {
            f16x8 bf = *(const f16x8*)(Bs + (j * 16 + l15) * 40 + quad * 8);
            acc[0][j] = __builtin_amdgcn_mfma_f32_16x16x32_f16(af[0], bf, acc[0][j], 0, 0, 0);
            acc[1][j] = __builtin_amdgcn_mfma_f32_16x16x32_f16(af[1], bf, acc[1][j], 0, 0, 0);
        }
        __syncthreads();
    }
    float* outp = nh ? outB : outA;
    #pragma unroll
    for (int i = 0; i < 2; ++i)
        #pragma unroll
        for (int r = 0; r < 4; ++r) {
            int c = c0 + wm + i * 16 + quad * 4 + r;
            float ri = rowinvl[b * LC_ + c];
            float* orow = outp + ((long long)b * LC_ + c) * D_ + l15;
            #pragma unroll
            for (int j = 0; j < 16; ++j)
                orow[j * 16] = acc[i][j][r] * ri;
        }
}

extern "C" void kernel_launch(void* const* d_in, const int* in_sizes, int n_in,
                              void* d_out, int out_size, void* d_ws, size_t ws_size,
                              hipStream_t stream) {
    const float* ctx   = (const float*)d_in[0];
    const float* qry   = (const float*)d_in[1];
    const int*   cmask = (const int*)d_in[2];
    const int*   qmask = (const int*)d_in[3];
    const float* w0    = (const float*)d_in[4];
    float* out = (float*)d_out;

    char* w = (char*)d_ws;
    float* sc      = (float*)w;  w += (long long)65536 * 4;
    float* sq      = (float*)w;  w += (long long)8192 * 4;
    float* rowm    = (float*)w;  w += (long long)65536 * 4;
    float* rowinvl = (float*)w;  w += (long long)65536 * 4;
    float* colm    = (float*)w;  w += (long long)8192 * 4;
    float* colinvl = (float*)w;  w += (long long)8192 * 4;
    float* pm      = (float*)w;  w += (long long)524288 * 4;
    float* pl      = (float*)w;  w += (long long)524288 * 4;
    f16*   sim16   = (f16*)w;    w += (long long)16777216 * 2;
    f16*   ctx16   = (f16*)w;    w += (long long)16777216 * 2;
    f16*   qrywm16 = (f16*)w;    w += (long long)2097152 * 2;
    f16*   Bcat    = (f16*)w;    w += (long long)4194304 * 2;

    k_prep<<<18432, 256, 0, stream>>>(ctx, qry, w0, ctx16, qrywm16, sc, sq);
    k_tq<<<dim3(4, 4, 32), 256, 0, stream>>>(qry, Bcat);
    k_f1<<<dim3(16, 32), 256, 0, stream>>>(ctx16, qrywm16, sc, sq, cmask, qmask,
        sim16, rowm, rowinvl, pm, pl);
    k_colreduce<<<32, 256, 0, stream>>>(pm, pl, colm, colinvl);
    k_g3<<<dim3(32, 8), 256, 0, stream>>>(ctx16, sim16, colm, colinvl, Bcat);
    k_f45<<<dim3(16, 2, 32), 256, 0, stream>>>(sim16, rowm, rowinvl, Bcat,
        out, out + (long long)B_ * LC_ * D_);
}